// Round 1
// baseline (1195.521 us; speedup 1.0000x reference)
//
#include <hip/hip_runtime.h>
#include <hip/hip_bf16.h>

#define B_   16
#define C_   256
#define H_   80
#define W_   256
#define HW_  (H_*W_)     // 20480
#define T_   128
#define T1_  129         // real tokens (time + 128 style)
#define TP_  160         // padded token dim for PV K (mult of 32)
#define NT1_ 9           // logits n-tiles: 9*16 = 144 >= 129
#define EPS_ 1e-5f

typedef __attribute__((ext_vector_type(8))) short short8;
typedef __attribute__((ext_vector_type(4))) float floatx4;

static __device__ __forceinline__ unsigned short f2bf(float f) {
  unsigned u = __float_as_uint(f);
  u += 0x7FFFu + ((u >> 16) & 1u);   // RNE
  return (unsigned short)(u >> 16);
}

// ---------------- Kernel 1: per-(b,c) mean / rstd over H*W ----------------
__global__ __launch_bounds__(256) void stats_kernel(const float* __restrict__ x,
                                                    float* __restrict__ meanArr,
                                                    float* __restrict__ rstdArr) {
  int bc = blockIdx.x;                       // 0..4095
  int tid = threadIdx.x;
  const floatx4* xv = (const floatx4*)(x + (size_t)bc * HW_);
  float s = 0.f, sq = 0.f;
  #pragma unroll
  for (int it = 0; it < HW_ / 4 / 256; ++it) {   // 20 iters
    floatx4 v = xv[it * 256 + tid];
    s  += v.x + v.y + v.z + v.w;
    sq += v.x*v.x + v.y*v.y + v.z*v.z + v.w*v.w;
  }
  __shared__ float rs[256], rq[256];
  rs[tid] = s; rq[tid] = sq;
  __syncthreads();
  for (int st = 128; st > 0; st >>= 1) {
    if (tid < st) { rs[tid] += rs[tid + st]; rq[tid] += rq[tid + st]; }
    __syncthreads();
  }
  if (tid == 0) {
    float mean = rs[0] / (float)HW_;
    float var  = rq[0] / (float)HW_ - mean * mean;
    meanArr[bc] = mean;
    rstdArr[bc] = rsqrtf(var + EPS_);
  }
}

// ---------------- Kernel 2: transpose Wk, Wv, Wl (256x256 each) ----------------
__global__ void transpose_kernel(const float* __restrict__ Wk, const float* __restrict__ Wv,
                                 const float* __restrict__ Wl,
                                 float* __restrict__ WkT, float* __restrict__ WvT,
                                 float* __restrict__ WlT) {
  int mat = blockIdx.x >> 8;
  int c   = blockIdx.x & 255;
  int d   = threadIdx.x;
  const float* src = (mat == 0) ? Wk : ((mat == 1) ? Wv : Wl);
  float* dst       = (mat == 0) ? WkT : ((mat == 1) ? WvT : WlT);
  dst[c * 256 + d] = src[d * 256 + c];
}

// ---------------- Kernel 3: per-(b, 8 tokens) prep ----------------
// k[t,d] = sum_c s[t,c]*Wk[d,c]; v likewise.
// G[t,c] = (sum_d k[t,d]*Wq[d,c]) / 16 ; kqs = G*rstd (bf16, 0 if masked)
// bias[t] = -sum_c kqs_fp32*mean  (or -10000 masked, -1e30 pad)
// vlT[e,t] = sum_d v[t,d]*Wl[e,d] (bf16, stored t-contiguous)
__global__ __launch_bounds__(256) void kv_kernel(
    const float* __restrict__ sty, const float* __restrict__ sty_mask,
    const float* __restrict__ timeArr, const float* __restrict__ Wq,
    const float* __restrict__ WkT, const float* __restrict__ WvT,
    const float* __restrict__ WlT,
    const float* __restrict__ meanArr, const float* __restrict__ rstdArr,
    unsigned short* __restrict__ kqs, unsigned short* __restrict__ vlT,
    float* __restrict__ biasArr) {
  int b  = blockIdx.x;
  int t0 = blockIdx.y * 8;
  int tid = threadIdx.x;
  __shared__ float s_lds[8][256], k_lds[8][256], v_lds[8][256], red[256];

  #pragma unroll
  for (int tt = 0; tt < 8; ++tt) {
    int t = t0 + tt;
    float v = 0.f;
    if (t == 0)        v = timeArr[b * 256 + tid];
    else if (t < T1_)  v = sty[((size_t)(b * 256 + tid)) * T_ + (t - 1)];
    s_lds[tt][tid] = v;
  }
  __syncthreads();

  float ka[8] = {0,0,0,0,0,0,0,0}, va[8] = {0,0,0,0,0,0,0,0};
  for (int c = 0; c < 256; ++c) {
    float wk = WkT[c * 256 + tid], wv = WvT[c * 256 + tid];
    #pragma unroll
    for (int tt = 0; tt < 8; ++tt) {
      float sv = s_lds[tt][c];
      ka[tt] = fmaf(sv, wk, ka[tt]);
      va[tt] = fmaf(sv, wv, va[tt]);
    }
  }
  #pragma unroll
  for (int tt = 0; tt < 8; ++tt) { k_lds[tt][tid] = ka[tt]; v_lds[tt][tid] = va[tt]; }
  __syncthreads();

  float G[8] = {0,0,0,0,0,0,0,0}, VL[8] = {0,0,0,0,0,0,0,0};
  for (int d = 0; d < 256; ++d) {
    float wq = Wq[d * 256 + tid], wl = WlT[d * 256 + tid];
    #pragma unroll
    for (int tt = 0; tt < 8; ++tt) {
      G[tt]  = fmaf(k_lds[tt][d], wq, G[tt]);
      VL[tt] = fmaf(v_lds[tt][d], wl, VL[tt]);
    }
  }

  float rho = rstdArr[b * 256 + tid], mu = meanArr[b * 256 + tid];
  for (int tt = 0; tt < 8; ++tt) {
    int t = t0 + tt;
    float kq_c = 0.f, vl_c = 0.f, maskv = 1.f;
    if (t < T1_) {
      maskv = (t == 0) ? 1.f : sty_mask[b * T_ + (t - 1)];
      kq_c = G[tt] * 0.0625f * rho;     // 1/sqrt(256) = 1/16
      if (maskv == 0.f) kq_c = 0.f;
      vl_c = VL[tt];
    }
    kqs[((size_t)b * TP_ + t) * 256 + tid]  = f2bf(kq_c);
    vlT[((size_t)b * 256 + tid) * TP_ + t]  = f2bf(vl_c);
    red[tid] = kq_c * mu;
    __syncthreads();
    for (int st = 128; st > 0; st >>= 1) {
      if (tid < st) red[tid] += red[tid + st];
      __syncthreads();
    }
    if (tid == 0) {
      float bv;
      if (t >= T1_)           bv = -1e30f;
      else if (maskv == 0.f)  bv = -10000.f;
      else                    bv = -red[0];
      biasArr[b * TP_ + t] = bv;
    }
    __syncthreads();
  }
}

// ---------------- Kernel 4: fused main ----------------
// Per block: 64 pixels (4 waves x 16). Phase1: logits = x @ kqs^T + bias (MFMA),
// softmax over t in-register (16-lane shfl), P -> LDS (bf16), Phase2: out2 = P @ vl,
// epilogue: out = (x + out2) * x_mask.
__global__ __launch_bounds__(256) void main_kernel(
    const float* __restrict__ x, const float* __restrict__ xmask,
    const unsigned short* __restrict__ kqs, const unsigned short* __restrict__ vlT,
    const float* __restrict__ biasArr, float* __restrict__ out) {
  int b    = blockIdx.y;
  int pix0 = blockIdx.x * 64;
  int wv   = threadIdx.x >> 6;
  int lane = threadIdx.x & 63;
  int g = lane >> 4, r = lane & 15;
  int p0w = pix0 + wv * 16;

  const float*          xb   = x    + (size_t)b * C_ * HW_;
  const unsigned short* kq_b = kqs  + (size_t)b * TP_ * 256;
  const unsigned short* vl_b = vlT  + (size_t)b * 256 * TP_;

  __shared__ unsigned short ps[4][16][168];   // [wave][pixel-row][token] bf16

  // ---- Phase 1: logits ----
  floatx4 acc[NT1_] = {};
  #pragma unroll
  for (int kt = 0; kt < 8; ++kt) {
    int cbase = kt * 32 + g * 8;
    const float* xp = xb + (size_t)cbase * HW_ + p0w + r;
    union { short8 v; unsigned short u[8]; } a;
    #pragma unroll
    for (int j = 0; j < 8; ++j) a.u[j] = f2bf(xp[(size_t)j * HW_]);
    #pragma unroll
    for (int nt = 0; nt < NT1_; ++nt) {
      short8 bb = *reinterpret_cast<const short8*>(kq_b + (nt * 16 + r) * 256 + cbase);
      acc[nt] = __builtin_amdgcn_mfma_f32_16x16x32_bf16(a.v, bb, acc[nt], 0, 0, 0);
    }
  }

  // ---- bias + softmax over t (per pixel row) ----
  float bias_l[NT1_];
  #pragma unroll
  for (int nt = 0; nt < NT1_; ++nt) bias_l[nt] = biasArr[b * TP_ + nt * 16 + r];

  float mrow[4] = {-3.0e38f, -3.0e38f, -3.0e38f, -3.0e38f};
  #pragma unroll
  for (int nt = 0; nt < NT1_; ++nt)
    #pragma unroll
    for (int i = 0; i < 4; ++i) {
      float v = acc[nt][i] + bias_l[nt];
      acc[nt][i] = v;
      mrow[i] = fmaxf(mrow[i], v);
    }
  #pragma unroll
  for (int msk = 1; msk < 16; msk <<= 1)
    #pragma unroll
    for (int i = 0; i < 4; ++i) mrow[i] = fmaxf(mrow[i], __shfl_xor(mrow[i], msk, 64));

  float srow[4] = {0.f, 0.f, 0.f, 0.f};
  #pragma unroll
  for (int nt = 0; nt < NT1_; ++nt)
    #pragma unroll
    for (int i = 0; i < 4; ++i) {
      float p = __expf(acc[nt][i] - mrow[i]);
      acc[nt][i] = p;
      srow[i] += p;
    }
  #pragma unroll
  for (int msk = 1; msk < 16; msk <<= 1)
    #pragma unroll
    for (int i = 0; i < 4; ++i) srow[i] += __shfl_xor(srow[i], msk, 64);

  float inv[4];
  #pragma unroll
  for (int i = 0; i < 4; ++i) inv[i] = 1.f / srow[i];

  // write P (D layout: row = 4g+i, col = nt*16+r) into LDS as [pixel][t]
  #pragma unroll
  for (int nt = 0; nt < NT1_; ++nt)
    #pragma unroll
    for (int i = 0; i < 4; ++i)
      ps[wv][g * 4 + i][nt * 16 + r] = f2bf(acc[nt][i] * inv[i]);
  // zero-fill padded tokens 144..159
  #pragma unroll
  for (int i = 0; i < 4; ++i) ps[wv][g * 4 + i][144 + r] = 0;
  __syncthreads();

  // ---- Phase 2: out2 = P @ vl ----
  floatx4 acc2[16] = {};
  #pragma unroll
  for (int ks = 0; ks < 5; ++ks) {
    short8 a2 = *reinterpret_cast<const short8*>(&ps[wv][r][ks * 32 + g * 8]);
    #pragma unroll
    for (int nt2 = 0; nt2 < 16; ++nt2) {
      short8 b2 = *reinterpret_cast<const short8*>(vl_b + (nt2 * 16 + r) * TP_ + ks * 32 + g * 8);
      acc2[nt2] = __builtin_amdgcn_mfma_f32_16x16x32_bf16(a2, b2, acc2[nt2], 0, 0, 0);
    }
  }

  // ---- Epilogue: out = (x + out2) * x_mask ----
  const float* xmb  = xmask + b * W_;
  float*       outb = out   + (size_t)b * C_ * HW_;
  float mk[4];
  #pragma unroll
  for (int i = 0; i < 4; ++i) mk[i] = xmb[(p0w + g * 4 + i) & (W_ - 1)];
  #pragma unroll
  for (int nt2 = 0; nt2 < 16; ++nt2) {
    int e = nt2 * 16 + r;
    size_t base = (size_t)e * HW_ + p0w + g * 4;
    #pragma unroll
    for (int i = 0; i < 4; ++i)
      outb[base + i] = (xb[base + i] + acc2[nt2][i]) * mk[i];
  }
}

// ---------------- launch ----------------
extern "C" void kernel_launch(void* const* d_in, const int* in_sizes, int n_in,
                              void* d_out, int out_size, void* d_ws, size_t ws_size,
                              hipStream_t stream) {
  const float* x        = (const float*)d_in[0];
  const float* x_mask   = (const float*)d_in[1];
  const float* sty      = (const float*)d_in[2];
  const float* sty_mask = (const float*)d_in[3];
  const float* timeArr  = (const float*)d_in[4];
  const float* Wq       = (const float*)d_in[5];
  const float* Wk       = (const float*)d_in[6];
  const float* Wv       = (const float*)d_in[7];
  const float* Wl       = (const float*)d_in[8];
  float* out = (float*)d_out;

  char* ws = (char*)d_ws;
  float* meanArr = (float*)(ws + 0);             // 4096 f32 = 16384 B
  float* rstdArr = (float*)(ws + 16384);         // 16384 B
  float* biasArr = (float*)(ws + 32768);         // 16*160*4 = 10240 B
  float* WkT     = (float*)(ws + 43008);         // 262144 B
  float* WvT     = (float*)(ws + 305152);        // 262144 B
  float* WlT     = (float*)(ws + 567296);        // 262144 B
  unsigned short* kqs = (unsigned short*)(ws + 829440);    // 16*160*256*2 = 1310720 B
  unsigned short* vlT = (unsigned short*)(ws + 2140160);   // 16*256*160*2 = 1310720 B
  // total ~3.45 MB of d_ws

  stats_kernel<<<dim3(4096), 256, 0, stream>>>(x, meanArr, rstdArr);
  transpose_kernel<<<dim3(768), 256, 0, stream>>>(Wk, Wv, Wl, WkT, WvT, WlT);
  kv_kernel<<<dim3(16, 20), 256, 0, stream>>>(sty, sty_mask, timeArr, Wq,
                                              WkT, WvT, WlT, meanArr, rstdArr,
                                              kqs, vlT, biasArr);
  main_kernel<<<dim3(320, 16), 256, 0, stream>>>(x, x_mask, kqs, vlT, biasArr, out);
}